// Round 1
// baseline (357.713 us; speedup 1.0000x reference)
//
#include <hip/hip_runtime.h>
#include <hip/hip_fp16.h>
#include <math.h>

// Problem constants (match reference)
#define R_TOT 4096
#define L_LEN 128
#define D_DIM 200
#define A_DIM 20
#define NEGK  2
#define B_SZ  1024
#define NNZ_C 20480
#define RN_TOT (R_TOT*NEGK)
#define VOCAB_C 32000
#define EPS_ 1e-12f
#define SLOT_CAP 64          // Poisson(20) max bin ~45; 64 is safe
#define NBUCK_BLK 160        // 160*256 = 40960 = 2*NNZ_C

__device__ __forceinline__ float4 unpack4(const uint2 u) {
  union { unsigned v; __half2 h; } c0, c1;
  c0.v = u.x; c1.v = u.y;
  const float2 f0 = __half22float2(c0.h);
  const float2 f1 = __half22float2(c1.h);
  return make_float4(f0.x, f0.y, f1.x, f1.y);
}

// ---------------- K0: cast emb -> fp16 table; block 0 also zeroes bucket counters ----------------
__global__ __launch_bounds__(256) void k_cast(
    const float* __restrict__ emb, ushort* __restrict__ emb_h, int* __restrict__ cnt)
{
  if (blockIdx.x == 0) {
    for (int i = threadIdx.x; i < 2*B_SZ; i += 256) cnt[i] = 0;
  }
  const int idx = blockIdx.x*256 + threadIdx.x;
  if (idx < (VOCAB_C*D_DIM)/4) {
    const float4 v = reinterpret_cast<const float4*>(emb)[idx];
    ushort4 o;
    o.x = __half_as_ushort(__float2half(v.x));
    o.y = __half_as_ushort(__float2half(v.y));
    o.z = __half_as_ushort(__float2half(v.z));
    o.w = __half_as_ushort(__float2half(v.w));
    reinterpret_cast<ushort4*>(emb_h)[idx] = o;
  }
}

// ---------------- K1: NEG means only + bucket tail ----------------
// Two rows per wave per iteration via uint4 (800 B / wave-instruction).
__global__ __launch_bounds__(256, 8) void k_means_neg(
    const int* __restrict__ neg, const ushort* __restrict__ emb_h,
    float* __restrict__ zn_all,
    const int* __restrict__ uidx, const float* __restrict__ uval,
    const int* __restrict__ iidx, const float* __restrict__ ival,
    int* __restrict__ cnt, int* __restrict__ scol, float* __restrict__ sval)
{
  const int sb = blockIdx.x;
  const int tid = threadIdx.x, lane = tid & 63, wv = tid >> 6;

  if (sb >= RN_TOT) {
    const int g = (sb - RN_TOT)*256 + tid;
    if (g < NNZ_C) {
      const int b = uidx[g];
      const int slot = atomicAdd(&cnt[b], 1);
      if (slot < SLOT_CAP) {
        scol[b*SLOT_CAP + slot] = uidx[NNZ_C + g];
        sval[b*SLOT_CAP + slot] = uval[g];
      }
    } else {
      const int g2 = g - NNZ_C;
      const int b = iidx[g2];
      const int slot = atomicAdd(&cnt[B_SZ + b], 1);
      if (slot < SLOT_CAP) {
        scol[(B_SZ + b)*SLOT_CAP + slot] = iidx[NNZ_C + g2];
        sval[(B_SZ + b)*SLOT_CAP + slot] = ival[g2];
      }
    }
    return;
  }

  __shared__ int widx[L_LEN];
  __shared__ __align__(16) float part[4][D_DIM];
  const int* src = neg + (size_t)sb*L_LEN;
  if (tid < L_LEN) widx[tid] = src[tid];
  __syncthreads();

  const int lh = lane & 31;          // column-chunk id (active if < 25)
  const int half = lane >> 5;        // 0 -> even row, 1 -> odd row
  float4 acc0 = {0.f,0.f,0.f,0.f}, acc1 = {0.f,0.f,0.f,0.f};
  for (int l = 2*wv; l < L_LEN; l += 8) {
    if (lh < 25) {
      const uint4 q = *reinterpret_cast<const uint4*>(
          emb_h + (size_t)widx[l + half]*D_DIM + 8*lh);   // 16B aligned (row = 400B)
      const float4 v0 = unpack4(make_uint2(q.x, q.y));
      const float4 v1 = unpack4(make_uint2(q.z, q.w));
      acc0.x += v0.x; acc0.y += v0.y; acc0.z += v0.z; acc0.w += v0.w;
      acc1.x += v1.x; acc1.y += v1.y; acc1.z += v1.z; acc1.w += v1.w;
    }
  }
  acc0.x += __shfl_xor(acc0.x, 32); acc0.y += __shfl_xor(acc0.y, 32);
  acc0.z += __shfl_xor(acc0.z, 32); acc0.w += __shfl_xor(acc0.w, 32);
  acc1.x += __shfl_xor(acc1.x, 32); acc1.y += __shfl_xor(acc1.y, 32);
  acc1.z += __shfl_xor(acc1.z, 32); acc1.w += __shfl_xor(acc1.w, 32);
  if (lane < 25) {
    *reinterpret_cast<float4*>(&part[wv][8*lane])     = acc0;
    *reinterpret_cast<float4*>(&part[wv][8*lane + 4]) = acc1;
  }
  __syncthreads();
  float* dst = zn_all + (size_t)sb*D_DIM;
  if (tid < D_DIM)
    dst[tid] = (part[0][tid] + part[1][tid] + part[2][tid] + part[3][tid]) * (1.0f/128.0f);
}

// ---------------- K2: fully fused per-review kernel ----------------
// ONE global gather pass per review: stage e_w -> LDS (fp16, 51.2 KB) while
// accumulating column partials (-> mean y_s), then vv = y_s @ Wm, dx, softmax,
// z_s, p_t, r_s, c1/c2 — all from LDS. Replaces pos-means + k_matvec + k_attn
// (3 global passes over e_w -> 1). 512 thr, ~67.6 KB LDS -> 2 blocks/CU.
__global__ __launch_bounds__(512, 4) void k_fused(
    const int* __restrict__ hist, const ushort* __restrict__ emb_h,
    const float* __restrict__ Wm, const float* __restrict__ Ww,
    const float* __restrict__ bw, const float* __restrict__ Wt,
    const float* __restrict__ zn_all,
    float* __restrict__ rs_out, float* __restrict__ abae)
{
  __shared__ __align__(16) ushort ew[L_LEN*D_DIM];   // 51200 B, (L,D) row-major fp16
  __shared__ __align__(16) float stg[16][D_DIM];     // 12800 B, mean/matvec partials
  __shared__ __align__(16) float ax[L_LEN];
  __shared__ __align__(16) float vv[D_DIM];
  __shared__ __align__(16) float zs[D_DIM];          // temp y_s, then real z_s
  __shared__ float ptile[160];
  __shared__ float red[80];
  __shared__ int widx[L_LEN];

  const int r = blockIdx.x;
  const int tid = threadIdx.x, lane = tid & 63, wv = tid >> 6;

  if (tid < L_LEN) widx[tid] = hist[r*L_LEN + tid];
  __syncthreads();

  // Phase A: gather e_w -> LDS + per-thread column partials (for the mean).
  // thread = (row-group j = tid>>5, chunk c5 = tid&31); fixed 8-col chunk per
  // thread across its 8 rows -> partials stay in registers; 8 independent
  // in-flight uint4 gathers per thread.
  {
    const int c5 = tid & 31;
    const int j  = tid >> 5;    // 0..15
    if (c5 < 25) {
      float p0=0.f,p1=0.f,p2=0.f,p3=0.f,p4=0.f,p5=0.f,p6=0.f,p7=0.f;
      #pragma unroll
      for (int k = 0; k < 8; ++k) {
        const int l = j + 16*k;
        const uint4 q = *reinterpret_cast<const uint4*>(
            emb_h + (size_t)widx[l]*D_DIM + 8*c5);           // 16B aligned
        *reinterpret_cast<uint4*>(ew + l*D_DIM + 8*c5) = q;
        const float4 v0 = unpack4(make_uint2(q.x, q.y));
        const float4 v1 = unpack4(make_uint2(q.z, q.w));
        p0 += v0.x; p1 += v0.y; p2 += v0.z; p3 += v0.w;
        p4 += v1.x; p5 += v1.y; p6 += v1.z; p7 += v1.w;
      }
      *reinterpret_cast<float4*>(&stg[j][8*c5])     = make_float4(p0,p1,p2,p3);
      *reinterpret_cast<float4*>(&stg[j][8*c5 + 4]) = make_float4(p4,p5,p6,p7);
    }
  }
  __syncthreads();

  // mean -> zs (used as y_s temp; overwritten by real z_s later)
  if (tid < D_DIM) {
    float s = 0.f;
    #pragma unroll
    for (int j2 = 0; j2 < 16; ++j2) s += stg[j2][tid];
    zs[tid] = s * (1.0f/128.0f);
  }
  __syncthreads();

  // Phase B: vv[k] = sum_d y_s[d] * Wm[d,k]  (split d-range over 2 groups)
  if (tid < 400) {
    const int k = tid % 200, h = tid / 200;
    float acc = 0.f;
    #pragma unroll 4
    for (int d = 100*h; d < 100*h + 100; ++d) acc += zs[d] * Wm[d*D_DIM + k];
    stg[h][k] = acc;
  }
  __syncthreads();
  if (tid < D_DIM) vv[tid] = stg[0][tid] + stg[1][tid];
  __syncthreads();

  // Phase C: dx[l] = e_w[l,:] . vv  — from LDS. 8 waves x 2 rows/iter.
  {
    const int lh = lane & 31;
    const int half = lane >> 5;
    float4 v8a = {0,0,0,0}, v8b = {0,0,0,0};
    if (lh < 25) {
      v8a = *reinterpret_cast<const float4*>(vv + 8*lh);
      v8b = *reinterpret_cast<const float4*>(vv + 8*lh + 4);
    }
    for (int l = 2*wv; l < L_LEN; l += 16) {
      float a0 = 0.f;
      if (lh < 25) {
        const uint4 q = *reinterpret_cast<const uint4*>(ew + (l + half)*D_DIM + 8*lh);
        const float4 e0 = unpack4(make_uint2(q.x, q.y));
        const float4 e1 = unpack4(make_uint2(q.z, q.w));
        a0 = e0.x*v8a.x + e0.y*v8a.y + e0.z*v8a.z + e0.w*v8a.w
           + e1.x*v8b.x + e1.y*v8b.y + e1.z*v8b.z + e1.w*v8b.w;
      }
      #pragma unroll
      for (int o = 16; o > 0; o >>= 1) a0 += __shfl_xor(a0, o);
      if (lh == 0) ax[l + half] = a0;
    }
  }
  __syncthreads();

  // softmax over 128 (wave 0 reduces)
  if (tid < 64) {
    float m = fmaxf(ax[tid], ax[tid+64]);
    #pragma unroll
    for (int o = 32; o > 0; o >>= 1) m = fmaxf(m, __shfl_xor(m, o));
    if (tid == 0) red[0] = m;
  }
  __syncthreads();
  const float M = red[0];
  if (tid < L_LEN) ax[tid] = expf(ax[tid] - M);
  __syncthreads();
  if (tid < 64) {
    float s = ax[tid] + ax[tid+64];
    #pragma unroll
    for (int o = 32; o > 0; o >>= 1) s += __shfl_xor(s, o);
    if (tid == 0) red[1] = s;
  }
  __syncthreads();
  const float Sinv = 1.0f / red[1];
  if (tid < L_LEN) ax[tid] *= Sinv;
  __syncthreads();

  // Phase E: z_s from LDS, flat (reshape) indexing. Quarter-wave per d-window.
  {
    const int lq = lane & 15;
    const int quad = lane >> 4;
    const float4 ax8a = *reinterpret_cast<const float4*>(ax + 8*lq);
    const float4 ax8b = *reinterpret_cast<const float4*>(ax + 8*lq + 4);
    for (int dq = wv; dq < 50; dq += 8) {
      const int d0 = 4*dq + quad;
      const int f0 = (d0 << 7) + 8*lq;      // flat half-index, 16B aligned
      const uint4 q = *reinterpret_cast<const uint4*>(ew + f0);
      const float4 e0 = unpack4(make_uint2(q.x, q.y));
      const float4 e1 = unpack4(make_uint2(q.z, q.w));
      float a = e0.x*ax8a.x + e0.y*ax8a.y + e0.z*ax8a.z + e0.w*ax8a.w
              + e1.x*ax8b.x + e1.y*ax8b.y + e1.z*ax8b.z + e1.w*ax8b.w;
      #pragma unroll
      for (int o = 8; o > 0; o >>= 1) a += __shfl_xor(a, o);
      if (lq == 0) zs[d0] = a;
    }
  }
  __syncthreads();

  // p_t[a] = z_s . Ww[a,:] + bw[a]  — 8x20 partials
  if (tid < 160) {
    const int a = tid % 20, j = tid / 20;
    float s = 0.f;
    #pragma unroll
    for (int i = 0; i < 25; ++i) {
      const int d = j + 8*i;
      s += zs[d] * Ww[a*D_DIM + d];
    }
    ptile[tid] = s;
  }
  __syncthreads();
  if (tid < A_DIM) {
    float s = bw[tid];
    #pragma unroll
    for (int j = 0; j < 8; ++j) s += ptile[j*20 + tid];
    red[2 + tid] = s;
  }
  __syncthreads();

  // r_s[d] = sum_a p_t[a]*Wt[d,a]; fused norms for c1 AND both c2 rows.
  // NOTE: reduction slots start at red[22] so they never clobber p_t (red[2..21]).
  float rsd = 0.f, zsd = 0.f, zn0 = 0.f, zn1 = 0.f;
  if (tid < D_DIM) {
    float acc = 0.f;
    #pragma unroll
    for (int a = 0; a < A_DIM; ++a) acc += red[2+a] * Wt[tid*A_DIM + a];
    rsd = acc; zsd = zs[tid];
    rs_out[(size_t)r*D_DIM + tid] = acc;
    zn0 = zn_all[(size_t)(2*r)*D_DIM + tid];
    zn1 = zn_all[(size_t)(2*r + 1)*D_DIM + tid];
  }
  float a0 = rsd*rsd, a1 = zsd*zsd, a2 = rsd*zsd;
  float b0 = zn0*zn0, b1 = zn0*rsd, b2 = zn1*zn1, b3 = zn1*rsd;
  #pragma unroll
  for (int o = 32; o > 0; o >>= 1) {
    a0 += __shfl_xor(a0, o); a1 += __shfl_xor(a1, o); a2 += __shfl_xor(a2, o);
    b0 += __shfl_xor(b0, o); b1 += __shfl_xor(b1, o);
    b2 += __shfl_xor(b2, o); b3 += __shfl_xor(b3, o);
  }
  if ((tid & 63) == 0) {
    red[22+wv] = a0; red[30+wv] = a1; red[38+wv] = a2;
    red[46+wv] = b0; red[54+wv] = b1; red[62+wv] = b2; red[70+wv] = b3;
  }
  __syncthreads();
  if (tid == 0) {
    float s0=0.f,s1=0.f,s2=0.f,t0=0.f,t1=0.f,t2=0.f,t3=0.f;
    #pragma unroll
    for (int i = 0; i < 8; ++i) {
      s0 += red[22+i]; s1 += red[30+i]; s2 += red[38+i];
      t0 += red[46+i]; t1 += red[54+i]; t2 += red[62+i]; t3 += red[70+i];
    }
    const float nr = fmaxf(sqrtf(s0), EPS_);
    const float nz = fmaxf(sqrtf(s1), EPS_);
    const float c1 = s2 / (nr * nz);
    const float c2a = t1 / (fmaxf(sqrtf(t0), EPS_) * nr);
    const float c2b = t3 / (fmaxf(sqrtf(t2), EPS_) * nr);
    abae[2*r]     = fmaxf(c2a - c1 + 1.0f, 0.0f);
    abae[2*r + 1] = fmaxf(c2b - c1 + 1.0f, 0.0f);
  }
}

// ---------------- K4: merged segment-sum apply + FM (one block per b) ----------------
__global__ __launch_bounds__(512) void k_aggfm(
    const int* __restrict__ cnt, const int* __restrict__ scol,
    const float* __restrict__ sval, const float* __restrict__ rs,
    const float* __restrict__ fcw, const float* __restrict__ V,
    float* __restrict__ uae, float* __restrict__ iae,
    float* __restrict__ linb, float* __restrict__ quadb)
{
  __shared__ __align__(16) float ivec[2*D_DIM];
  __shared__ float redw[8];
  __shared__ float qpart[10];
  const int b = blockIdx.x;
  const int tid = threadIdx.x, lane = tid & 63, wv = tid >> 6;

  if (tid < D_DIM) {
    int n = cnt[b]; n = n < SLOT_CAP ? n : SLOT_CAP;
    const int* cols = scol + (size_t)b*SLOT_CAP;
    const float* vals = sval + (size_t)b*SLOT_CAP;
    float acc = 0.f;
    for (int j = 0; j < n; ++j) acc += vals[j] * rs[(size_t)cols[j]*D_DIM + tid];
    ivec[tid] = acc;
    uae[(size_t)b*D_DIM + tid] = acc;
  } else if (tid >= 256 && tid < 256 + D_DIM) {
    const int t = tid - 256;
    int n = cnt[B_SZ + b]; n = n < SLOT_CAP ? n : SLOT_CAP;
    const int* cols = scol + (size_t)(B_SZ + b)*SLOT_CAP;
    const float* vals = sval + (size_t)(B_SZ + b)*SLOT_CAP;
    float acc = 0.f;
    for (int j = 0; j < n; ++j) acc += vals[j] * rs[(size_t)cols[j]*D_DIM + t];
    ivec[D_DIM + t] = acc;
    iae[(size_t)b*D_DIM + t] = acc;
  }
  __syncthreads();

  float lv = 0.f;
  if (tid < 2*D_DIM) lv = ivec[tid] * fcw[tid];
  #pragma unroll
  for (int o = 32; o > 0; o >>= 1) lv += __shfl_xor(lv, o);
  if (lane == 0) redw[wv] = lv;

  {
    const int k = wv;
    float s1 = 0.f, s2 = 0.f;
    for (int f = lane; f < 2*D_DIM; f += 64) {
      const float x = ivec[f];
      const float vk = V[f*10 + k];
      s1 += x*vk; s2 += x*x*vk*vk;
    }
    #pragma unroll
    for (int o = 32; o > 0; o >>= 1) { s1 += __shfl_xor(s1,o); s2 += __shfl_xor(s2,o); }
    if (lane == 0) qpart[k] = s1*s1 - s2;
  }
  if (wv < 2) {
    const int k = 8 + wv;
    float s1 = 0.f, s2 = 0.f;
    for (int f = lane; f < 2*D_DIM; f += 64) {
      const float x = ivec[f];
      const float vk = V[f*10 + k];
      s1 += x*vk; s2 += x*x*vk*vk;
    }
    #pragma unroll
    for (int o = 32; o > 0; o >>= 1) { s1 += __shfl_xor(s1,o); s2 += __shfl_xor(s2,o); }
    if (lane == 0) qpart[k] = s1*s1 - s2;
  }
  __syncthreads();
  if (tid == 0) {
    float lin = 0.f;
    #pragma unroll
    for (int i = 0; i < 8; ++i) lin += redw[i];
    float q = 0.f;
    #pragma unroll
    for (int i = 0; i < 10; ++i) q += qpart[i];
    linb[b] = lin; quadb[b] = q;
  }
}

// ---------------- K5: fused quad-reduce + prediction + all final scalars ----------------
__global__ __launch_bounds__(1024) void k_final2(
    const float* __restrict__ quadb, const float* __restrict__ linb,
    const float* __restrict__ fcb, const int* __restrict__ user,
    const int* __restrict__ item, const float* __restrict__ busers,
    const float* __restrict__ bitems, const float* __restrict__ label,
    const float* __restrict__ Wt, const float* __restrict__ abae,
    float* __restrict__ pred, float* __restrict__ rl, float* __restrict__ obj)
{
  __shared__ float sA[16], sB[16], sC[16];
  __shared__ float cninv[A_DIM];
  __shared__ float quad_s;
  const int tid = threadIdx.x;
  const int lane = tid & 63;
  const int wv = tid >> 6;

  float q = quadb[tid];
  #pragma unroll
  for (int o = 32; o > 0; o >>= 1) q += __shfl_xor(q, o);
  if (lane == 0) sA[wv] = q;

  if (tid < A_DIM) {
    float s = 0.f;
    for (int d = 0; d < D_DIM; ++d) { const float w = Wt[d*A_DIM + tid]; s += w*w; }
    cninv[tid] = 1.0f / fmaxf(sqrtf(s), EPS_);
  }
  __syncthreads();
  if (wv == 0) {
    float s = (lane < 16) ? sA[lane] : 0.f;
    #pragma unroll
    for (int o = 32; o > 0; o >>= 1) s += __shfl_xor(s, o);
    if (lane == 0) quad_s = s;
  }
  __syncthreads();

  const float p = 0.5f*quad_s + linb[tid] + fcb[0]
                + busers[user[tid]] + bitems[item[tid]];
  pred[tid] = p;
  const float dd = p - label[tid];
  const float myrl = dd*dd;
  rl[tid] = myrl;

  float u = 0.f;
  if (tid < 400) {
    const int a = tid / 20, c = tid % 20;
    float dot = 0.f;
    for (int d = 0; d < D_DIM; ++d) dot += Wt[d*A_DIM + a]*Wt[d*A_DIM + c];
    const float g = dot*cninv[a]*cninv[c] - (a==c ? 1.0f : 0.0f);
    u = g*g;
  }
  float js = 0.f;
  #pragma unroll
  for (int j = 0; j < 8; ++j) js += abae[tid + 1024*j];
  float ms = myrl;

  #pragma unroll
  for (int o = 32; o > 0; o >>= 1) {
    u += __shfl_xor(u,o); js += __shfl_xor(js,o); ms += __shfl_xor(ms,o);
  }
  if (lane == 0) { sA[wv] = u; sB[wv] = js; sC[wv] = ms; }
  __syncthreads();
  if (tid == 0) {
    float U = 0.f, J = 0.f, Ms = 0.f;
    for (int i = 0; i < 16; ++i) { U += sA[i]; J += sB[i]; Ms += sC[i]; }
    obj[0] = Ms/1024.0f + 0.01f*(J/8192.0f) + 0.01f*(U/400.0f);
  }
}

extern "C" void kernel_launch(void* const* d_in, const int* in_sizes, int n_in,
                              void* d_out, int out_size, void* d_ws, size_t ws_size,
                              hipStream_t stream) {
  const int*   hist   = (const int*)  d_in[0];
  const int*   neg    = (const int*)  d_in[1];
  const int*   user   = (const int*)  d_in[2];
  const int*   item   = (const int*)  d_in[3];
  const float* label  = (const float*)d_in[4];
  const int*   uidx   = (const int*)  d_in[5];
  const float* uval   = (const float*)d_in[6];
  const int*   iidx   = (const int*)  d_in[7];
  const float* ival   = (const float*)d_in[8];
  const float* emb    = (const float*)d_in[9];
  const float* Wm     = (const float*)d_in[10];
  const float* Ww     = (const float*)d_in[11];
  const float* bw     = (const float*)d_in[12];
  const float* Wt     = (const float*)d_in[13];
  const float* fcw    = (const float*)d_in[14];
  const float* fcb    = (const float*)d_in[15];
  const float* V      = (const float*)d_in[16];
  const float* busers = (const float*)d_in[17];
  const float* bitems = (const float*)d_in[18];

  float* out  = (float*)d_out;
  float* obj  = out;                       // 1
  float* rl   = out + 1;                   // 1024
  float* abae = out + 1 + B_SZ;            // 8192
  float* pred = out + 1 + B_SZ + RN_TOT;   // 1024
  float* uae  = pred + B_SZ;               // 204800
  float* iae  = uae + (size_t)B_SZ*D_DIM;  // 204800

  float* ws     = (float*)d_ws;
  float* rs     = ws;                              // R*D
  float* zn_all = rs + (size_t)R_TOT*D_DIM;        // RN*D
  float* linb   = zn_all + (size_t)RN_TOT*D_DIM;   // B
  float* quadb  = linb + B_SZ;                     // B
  float* sval   = quadb + B_SZ;                    // 2*B*SLOT_CAP floats
  int*   scol   = (int*)(sval + (size_t)2*B_SZ*SLOT_CAP);   // 2*B*SLOT_CAP ints
  int*   cnt    = scol + (size_t)2*B_SZ*SLOT_CAP;           // 2*B ints
  ushort* emb_h = (ushort*)(cnt + 2*B_SZ);                  // VOCAB*D halves

  const int cast_blocks = (VOCAB_C*D_DIM/4 + 255)/256;      // 6250

  k_cast     <<<cast_blocks, 256, 0, stream>>>(emb, emb_h, cnt);
  k_means_neg<<<RN_TOT + NBUCK_BLK, 256, 0, stream>>>(neg, emb_h, zn_all,
                                                      uidx, uval, iidx, ival,
                                                      cnt, scol, sval);
  k_fused    <<<R_TOT, 512, 0, stream>>>(hist, emb_h, Wm, Ww, bw, Wt,
                                         zn_all, rs, abae);
  k_aggfm    <<<B_SZ, 512, 0, stream>>>(cnt, scol, sval, rs, fcw, V,
                                        uae, iae, linb, quadb);
  k_final2   <<<1, 1024, 0, stream>>>(quadb, linb, fcb, user, item, busers, bitems,
                                      label, Wt, abae, pred, rl, obj);
}

// Round 2
// 312.469 us; speedup vs baseline: 1.1448x; 1.1448x over previous
//
#include <hip/hip_runtime.h>
#include <hip/hip_fp16.h>
#include <math.h>

// Problem constants (match reference)
#define R_TOT 4096
#define L_LEN 128
#define D_DIM 200
#define A_DIM 20
#define NEGK  2
#define B_SZ  1024
#define NNZ_C 20480
#define RN_TOT (R_TOT*NEGK)
#define S_TOT (R_TOT + RN_TOT)
#define VOCAB_C 32000
#define EPS_ 1e-12f
#define SLOT_CAP 64          // Poisson(20) max bin ~45; 64 is safe
#define NBUCK_BLK 160        // 160*256 = 40960 = 2*NNZ_C

__device__ __forceinline__ float4 unpack4(const uint2 u) {
  union { unsigned v; __half2 h; } c0, c1;
  c0.v = u.x; c1.v = u.y;
  const float2 f0 = __half22float2(c0.h);
  const float2 f1 = __half22float2(c1.h);
  return make_float4(f0.x, f0.y, f1.x, f1.y);
}

// ---------------- K0: cast emb -> fp16 table; block 0 also zeroes bucket counters ----------------
__global__ __launch_bounds__(256) void k_cast(
    const float* __restrict__ emb, ushort* __restrict__ emb_h, int* __restrict__ cnt)
{
  if (blockIdx.x == 0) {
    for (int i = threadIdx.x; i < 2*B_SZ; i += 256) cnt[i] = 0;
  }
  const int idx = blockIdx.x*256 + threadIdx.x;
  if (idx < (VOCAB_C*D_DIM)/4) {
    const float4 v = reinterpret_cast<const float4*>(emb)[idx];
    ushort4 o;
    o.x = __half_as_ushort(__float2half(v.x));
    o.y = __half_as_ushort(__float2half(v.y));
    o.z = __half_as_ushort(__float2half(v.z));
    o.w = __half_as_ushort(__float2half(v.w));
    reinterpret_cast<ushort4*>(emb_h)[idx] = o;
  }
}

// ---------------- K1: combined means (pos+neg) + bucket tail ----------------
// 4-deep independent uint4 gathers per thread (MLP upgrade vs round-0's 1-2).
// Thread (j = tid>>5 in 0..7, c5 = tid&31 < 25): rows l = j + 8k, cols 8c5..8c5+7.
__global__ __launch_bounds__(256, 8) void k_means2(
    const int* __restrict__ hist, const int* __restrict__ neg,
    const ushort* __restrict__ emb_h,
    float* __restrict__ ys_all, float* __restrict__ zn_all,
    const int* __restrict__ uidx, const float* __restrict__ uval,
    const int* __restrict__ iidx, const float* __restrict__ ival,
    int* __restrict__ cnt, int* __restrict__ scol, float* __restrict__ sval)
{
  const int sb = blockIdx.x;
  const int tid = threadIdx.x;

  if (sb >= S_TOT) {
    const int g = (sb - S_TOT)*256 + tid;
    if (g < NNZ_C) {
      const int b = uidx[g];
      const int slot = atomicAdd(&cnt[b], 1);
      if (slot < SLOT_CAP) {
        scol[b*SLOT_CAP + slot] = uidx[NNZ_C + g];
        sval[b*SLOT_CAP + slot] = uval[g];
      }
    } else {
      const int g2 = g - NNZ_C;
      const int b = iidx[g2];
      const int slot = atomicAdd(&cnt[B_SZ + b], 1);
      if (slot < SLOT_CAP) {
        scol[(B_SZ + b)*SLOT_CAP + slot] = iidx[NNZ_C + g2];
        sval[(B_SZ + b)*SLOT_CAP + slot] = ival[g2];
      }
    }
    return;
  }

  __shared__ int widx[L_LEN];
  __shared__ __align__(16) float part[8][D_DIM];
  const bool is_pos = (sb < R_TOT);
  const int* src = is_pos ? (hist + (size_t)sb*L_LEN)
                          : (neg + (size_t)(sb - R_TOT)*L_LEN);
  if (tid < L_LEN) widx[tid] = src[tid];
  __syncthreads();

  const int c5 = tid & 31;       // column chunk (active if < 25)
  const int j  = tid >> 5;       // 0..7 row group
  float4 sA = {0.f,0.f,0.f,0.f}, sB = {0.f,0.f,0.f,0.f};
  if (c5 < 25) {
    const size_t coff = 8*c5;
    #pragma unroll
    for (int k0 = 0; k0 < 16; k0 += 4) {
      const uint4 q0 = *reinterpret_cast<const uint4*>(
          emb_h + (size_t)widx[j + 8*(k0+0)]*D_DIM + coff);
      const uint4 q1 = *reinterpret_cast<const uint4*>(
          emb_h + (size_t)widx[j + 8*(k0+1)]*D_DIM + coff);
      const uint4 q2 = *reinterpret_cast<const uint4*>(
          emb_h + (size_t)widx[j + 8*(k0+2)]*D_DIM + coff);
      const uint4 q3 = *reinterpret_cast<const uint4*>(
          emb_h + (size_t)widx[j + 8*(k0+3)]*D_DIM + coff);
      float4 e;
      e = unpack4(make_uint2(q0.x,q0.y)); sA.x+=e.x; sA.y+=e.y; sA.z+=e.z; sA.w+=e.w;
      e = unpack4(make_uint2(q0.z,q0.w)); sB.x+=e.x; sB.y+=e.y; sB.z+=e.z; sB.w+=e.w;
      e = unpack4(make_uint2(q1.x,q1.y)); sA.x+=e.x; sA.y+=e.y; sA.z+=e.z; sA.w+=e.w;
      e = unpack4(make_uint2(q1.z,q1.w)); sB.x+=e.x; sB.y+=e.y; sB.z+=e.z; sB.w+=e.w;
      e = unpack4(make_uint2(q2.x,q2.y)); sA.x+=e.x; sA.y+=e.y; sA.z+=e.z; sA.w+=e.w;
      e = unpack4(make_uint2(q2.z,q2.w)); sB.x+=e.x; sB.y+=e.y; sB.z+=e.z; sB.w+=e.w;
      e = unpack4(make_uint2(q3.x,q3.y)); sA.x+=e.x; sA.y+=e.y; sA.z+=e.z; sA.w+=e.w;
      e = unpack4(make_uint2(q3.z,q3.w)); sB.x+=e.x; sB.y+=e.y; sB.z+=e.z; sB.w+=e.w;
    }
    *reinterpret_cast<float4*>(&part[j][8*c5])     = sA;
    *reinterpret_cast<float4*>(&part[j][8*c5 + 4]) = sB;
  }
  __syncthreads();
  float* dst = is_pos ? (ys_all + (size_t)sb*D_DIM)
                      : (zn_all + (size_t)(sb - R_TOT)*D_DIM);
  if (tid < D_DIM) {
    float a = 0.f;
    #pragma unroll
    for (int j2 = 0; j2 < 8; ++j2) a += part[j2][tid];
    dst[tid] = a * (1.0f/128.0f);
  }
}

// ---------------- K2: V = Y @ Wm (16 reviews/block) ----------------
#define KB_RT 16
__global__ __launch_bounds__(256, 2) void k_matvec(
    const float* __restrict__ ys_all, const float* __restrict__ Wm,
    float* __restrict__ vv_all)
{
  __shared__ float ysl[KB_RT][D_DIM];
  const int r0 = blockIdx.x * KB_RT;
  const int tid = threadIdx.x;
  for (int i = tid; i < KB_RT*D_DIM; i += 256)
    ysl[i / D_DIM][i % D_DIM] = ys_all[(size_t)r0*D_DIM + i];
  __syncthreads();
  if (tid < D_DIM) {
    float acc[KB_RT];
    #pragma unroll
    for (int r = 0; r < KB_RT; ++r) acc[r] = 0.f;
    #pragma unroll 4
    for (int k = 0; k < D_DIM; ++k) {
      const float w = Wm[k*D_DIM + tid];
      #pragma unroll
      for (int r = 0; r < KB_RT; ++r) acc[r] += ysl[r][k] * w;
    }
    #pragma unroll
    for (int r = 0; r < KB_RT; ++r)
      vv_all[(size_t)(r0 + r)*D_DIM + tid] = acc[r];
  }
}

// ---------------- K3: attn — ONE gather pass (dx computed during staging), z_s from LDS ----------------
// Staging: thread (j = tid>>5 in 0..15, c5 = tid&31 < 25) gathers rows l = j+16k
// (8 independent uint4 loads), stores to ew LDS AND accumulates dx partial
// p[k] = e[l, 8c5..8c5+7] . vv[8c5..] (vv in registers). Half-wave shuffle
// reduce over c5 -> dx. Then softmax, z_s from LDS (flat reshape), p_t, r_s,
// c1/c2 epilogue. LDS 53.4 KB -> 3 blocks/CU (24 waves).
__global__ __launch_bounds__(512, 6) void k_attn(
    const int* __restrict__ hist, const ushort* __restrict__ emb_h,
    const float* __restrict__ vv_all,
    const float* __restrict__ Ww, const float* __restrict__ bw,
    const float* __restrict__ Wt, const float* __restrict__ zn_all,
    float* __restrict__ rs_out, float* __restrict__ abae)
{
  __shared__ __align__(16) ushort ew[L_LEN*D_DIM];   // 51200 B, (L,D) row-major fp16
  __shared__ __align__(16) float ax[L_LEN];          // 512 B
  __shared__ __align__(16) float zs[D_DIM];          // 800 B
  // union region: widx (512 B) lives only during staging; ptile+red (960 B) after
  __shared__ __align__(16) float ubuf[240];          // 960 B
  int*   widx  = reinterpret_cast<int*>(ubuf);       // [0..128)
  float* ptile = ubuf;                               // [0..160)
  float* red   = ubuf + 160;                         // [160..240)

  const int r = blockIdx.x;
  const int tid = threadIdx.x, lane = tid & 63, wv = tid >> 6;

  if (tid < L_LEN) widx[tid] = hist[r*L_LEN + tid];
  __syncthreads();

  // ---- staging + dx ----
  {
    const int c5 = tid & 31;
    const int j  = tid >> 5;     // 0..15
    float4 v8a = {0,0,0,0}, v8b = {0,0,0,0};
    if (c5 < 25) {
      v8a = *reinterpret_cast<const float4*>(vv_all + (size_t)r*D_DIM + 8*c5);
      v8b = *reinterpret_cast<const float4*>(vv_all + (size_t)r*D_DIM + 8*c5 + 4);
    }
    float p0=0.f,p1=0.f,p2=0.f,p3=0.f,p4=0.f,p5=0.f,p6=0.f,p7=0.f;
    if (c5 < 25) {
      const size_t coff = 8*c5;
      #pragma unroll
      for (int k = 0; k < 8; ++k) {
        const int l = j + 16*k;
        const uint4 q = *reinterpret_cast<const uint4*>(
            emb_h + (size_t)widx[l]*D_DIM + coff);
        *reinterpret_cast<uint4*>(ew + l*D_DIM + coff) = q;
        const float4 e0 = unpack4(make_uint2(q.x, q.y));
        const float4 e1 = unpack4(make_uint2(q.z, q.w));
        const float d = e0.x*v8a.x + e0.y*v8a.y + e0.z*v8a.z + e0.w*v8a.w
                      + e1.x*v8b.x + e1.y*v8b.y + e1.z*v8b.z + e1.w*v8b.w;
        if (k==0) p0=d; else if (k==1) p1=d; else if (k==2) p2=d; else if (k==3) p3=d;
        else if (k==4) p4=d; else if (k==5) p5=d; else if (k==6) p6=d; else p7=d;
      }
    }
    // reduce over c5 (32 lanes of a half-wave; inactive lanes contribute 0)
    #pragma unroll
    for (int o = 16; o > 0; o >>= 1) {
      p0 += __shfl_xor(p0, o); p1 += __shfl_xor(p1, o);
      p2 += __shfl_xor(p2, o); p3 += __shfl_xor(p3, o);
      p4 += __shfl_xor(p4, o); p5 += __shfl_xor(p5, o);
      p6 += __shfl_xor(p6, o); p7 += __shfl_xor(p7, o);
    }
    if (c5 == 0) {
      ax[j]      = p0; ax[j + 16]  = p1; ax[j + 32]  = p2; ax[j + 48]  = p3;
      ax[j + 64] = p4; ax[j + 80]  = p5; ax[j + 96]  = p6; ax[j + 112] = p7;
    }
  }
  __syncthreads();
  // NOTE: widx is dead from here on; ptile/red may now use ubuf.

  // ---- softmax over 128 (wave 0 reduces) ----
  if (tid < 64) {
    float m = fmaxf(ax[tid], ax[tid+64]);
    #pragma unroll
    for (int o = 32; o > 0; o >>= 1) m = fmaxf(m, __shfl_xor(m, o));
    if (tid == 0) red[0] = m;
  }
  __syncthreads();
  const float M = red[0];
  if (tid < L_LEN) ax[tid] = expf(ax[tid] - M);
  __syncthreads();
  if (tid < 64) {
    float s = ax[tid] + ax[tid+64];
    #pragma unroll
    for (int o = 32; o > 0; o >>= 1) s += __shfl_xor(s, o);
    if (tid == 0) red[1] = s;
  }
  __syncthreads();
  const float Sinv = 1.0f / red[1];
  if (tid < L_LEN) ax[tid] *= Sinv;
  __syncthreads();

  // ---- z_s from LDS, flat (reshape) indexing. Quarter-wave per d-window ----
  {
    const int lq = lane & 15;
    const int quad = lane >> 4;
    const float4 ax8a = *reinterpret_cast<const float4*>(ax + 8*lq);
    const float4 ax8b = *reinterpret_cast<const float4*>(ax + 8*lq + 4);
    for (int dq = wv; dq < 50; dq += 8) {
      const int d0 = 4*dq + quad;
      const int f0 = (d0 << 7) + 8*lq;      // flat half-index, 16B aligned
      const uint4 q = *reinterpret_cast<const uint4*>(ew + f0);
      const float4 e0 = unpack4(make_uint2(q.x, q.y));
      const float4 e1 = unpack4(make_uint2(q.z, q.w));
      float a = e0.x*ax8a.x + e0.y*ax8a.y + e0.z*ax8a.z + e0.w*ax8a.w
              + e1.x*ax8b.x + e1.y*ax8b.y + e1.z*ax8b.z + e1.w*ax8b.w;
      #pragma unroll
      for (int o = 8; o > 0; o >>= 1) a += __shfl_xor(a, o);
      if (lq == 0) zs[d0] = a;
    }
  }
  __syncthreads();

  // ---- p_t[a] = z_s . Ww[a,:] + bw[a] — 8x20 partials ----
  if (tid < 160) {
    const int a = tid % 20, j = tid / 20;
    float s = 0.f;
    #pragma unroll
    for (int i = 0; i < 25; ++i) {
      const int d = j + 8*i;
      s += zs[d] * Ww[a*D_DIM + d];
    }
    ptile[tid] = s;
  }
  __syncthreads();
  if (tid < A_DIM) {
    float s = bw[tid];
    #pragma unroll
    for (int j = 0; j < 8; ++j) s += ptile[j*20 + tid];
    red[2 + tid] = s;
  }
  __syncthreads();

  // ---- r_s + fused norms for c1 and both c2 rows ----
  float rsd = 0.f, zsd = 0.f, zn0 = 0.f, zn1 = 0.f;
  if (tid < D_DIM) {
    float acc = 0.f;
    #pragma unroll
    for (int a = 0; a < A_DIM; ++a) acc += red[2+a] * Wt[tid*A_DIM + a];
    rsd = acc; zsd = zs[tid];
    rs_out[(size_t)r*D_DIM + tid] = acc;
    zn0 = zn_all[(size_t)(2*r)*D_DIM + tid];
    zn1 = zn_all[(size_t)(2*r + 1)*D_DIM + tid];
  }
  float a0 = rsd*rsd, a1 = zsd*zsd, a2 = rsd*zsd;
  float b0 = zn0*zn0, b1 = zn0*rsd, b2 = zn1*zn1, b3 = zn1*rsd;
  #pragma unroll
  for (int o = 32; o > 0; o >>= 1) {
    a0 += __shfl_xor(a0, o); a1 += __shfl_xor(a1, o); a2 += __shfl_xor(a2, o);
    b0 += __shfl_xor(b0, o); b1 += __shfl_xor(b1, o);
    b2 += __shfl_xor(b2, o); b3 += __shfl_xor(b3, o);
  }
  if ((tid & 63) == 0) {
    red[22+wv] = a0; red[30+wv] = a1; red[38+wv] = a2;
    red[46+wv] = b0; red[54+wv] = b1; red[62+wv] = b2; red[70+wv] = b3;
  }
  __syncthreads();
  if (tid == 0) {
    float s0=0.f,s1=0.f,s2=0.f,t0=0.f,t1=0.f,t2=0.f,t3=0.f;
    #pragma unroll
    for (int i = 0; i < 8; ++i) {
      s0 += red[22+i]; s1 += red[30+i]; s2 += red[38+i];
      t0 += red[46+i]; t1 += red[54+i]; t2 += red[62+i]; t3 += red[70+i];
    }
    const float nr = fmaxf(sqrtf(s0), EPS_);
    const float nz = fmaxf(sqrtf(s1), EPS_);
    const float c1 = s2 / (nr * nz);
    const float c2a = t1 / (fmaxf(sqrtf(t0), EPS_) * nr);
    const float c2b = t3 / (fmaxf(sqrtf(t2), EPS_) * nr);
    abae[2*r]     = fmaxf(c2a - c1 + 1.0f, 0.0f);
    abae[2*r + 1] = fmaxf(c2b - c1 + 1.0f, 0.0f);
  }
}

// ---------------- K4: merged segment-sum apply + FM (one block per b) ----------------
__global__ __launch_bounds__(512) void k_aggfm(
    const int* __restrict__ cnt, const int* __restrict__ scol,
    const float* __restrict__ sval, const float* __restrict__ rs,
    const float* __restrict__ fcw, const float* __restrict__ V,
    float* __restrict__ uae, float* __restrict__ iae,
    float* __restrict__ linb, float* __restrict__ quadb)
{
  __shared__ __align__(16) float ivec[2*D_DIM];
  __shared__ float redw[8];
  __shared__ float qpart[10];
  const int b = blockIdx.x;
  const int tid = threadIdx.x, lane = tid & 63, wv = tid >> 6;

  if (tid < D_DIM) {
    int n = cnt[b]; n = n < SLOT_CAP ? n : SLOT_CAP;
    const int* cols = scol + (size_t)b*SLOT_CAP;
    const float* vals = sval + (size_t)b*SLOT_CAP;
    float acc = 0.f;
    for (int j = 0; j < n; ++j) acc += vals[j] * rs[(size_t)cols[j]*D_DIM + tid];
    ivec[tid] = acc;
    uae[(size_t)b*D_DIM + tid] = acc;
  } else if (tid >= 256 && tid < 256 + D_DIM) {
    const int t = tid - 256;
    int n = cnt[B_SZ + b]; n = n < SLOT_CAP ? n : SLOT_CAP;
    const int* cols = scol + (size_t)(B_SZ + b)*SLOT_CAP;
    const float* vals = sval + (size_t)(B_SZ + b)*SLOT_CAP;
    float acc = 0.f;
    for (int j = 0; j < n; ++j) acc += vals[j] * rs[(size_t)cols[j]*D_DIM + t];
    ivec[D_DIM + t] = acc;
    iae[(size_t)b*D_DIM + t] = acc;
  }
  __syncthreads();

  float lv = 0.f;
  if (tid < 2*D_DIM) lv = ivec[tid] * fcw[tid];
  #pragma unroll
  for (int o = 32; o > 0; o >>= 1) lv += __shfl_xor(lv, o);
  if (lane == 0) redw[wv] = lv;

  {
    const int k = wv;
    float s1 = 0.f, s2 = 0.f;
    for (int f = lane; f < 2*D_DIM; f += 64) {
      const float x = ivec[f];
      const float vk = V[f*10 + k];
      s1 += x*vk; s2 += x*x*vk*vk;
    }
    #pragma unroll
    for (int o = 32; o > 0; o >>= 1) { s1 += __shfl_xor(s1,o); s2 += __shfl_xor(s2,o); }
    if (lane == 0) qpart[k] = s1*s1 - s2;
  }
  if (wv < 2) {
    const int k = 8 + wv;
    float s1 = 0.f, s2 = 0.f;
    for (int f = lane; f < 2*D_DIM; f += 64) {
      const float x = ivec[f];
      const float vk = V[f*10 + k];
      s1 += x*vk; s2 += x*x*vk*vk;
    }
    #pragma unroll
    for (int o = 32; o > 0; o >>= 1) { s1 += __shfl_xor(s1,o); s2 += __shfl_xor(s2,o); }
    if (lane == 0) qpart[k] = s1*s1 - s2;
  }
  __syncthreads();
  if (tid == 0) {
    float lin = 0.f;
    #pragma unroll
    for (int i = 0; i < 8; ++i) lin += redw[i];
    float q = 0.f;
    #pragma unroll
    for (int i = 0; i < 10; ++i) q += qpart[i];
    linb[b] = lin; quadb[b] = q;
  }
}

// ---------------- K5: fused quad-reduce + prediction + all final scalars ----------------
__global__ __launch_bounds__(1024) void k_final2(
    const float* __restrict__ quadb, const float* __restrict__ linb,
    const float* __restrict__ fcb, const int* __restrict__ user,
    const int* __restrict__ item, const float* __restrict__ busers,
    const float* __restrict__ bitems, const float* __restrict__ label,
    const float* __restrict__ Wt, const float* __restrict__ abae,
    float* __restrict__ pred, float* __restrict__ rl, float* __restrict__ obj)
{
  __shared__ float sA[16], sB[16], sC[16];
  __shared__ float cninv[A_DIM];
  __shared__ float quad_s;
  const int tid = threadIdx.x;
  const int lane = tid & 63;
  const int wv = tid >> 6;

  float q = quadb[tid];
  #pragma unroll
  for (int o = 32; o > 0; o >>= 1) q += __shfl_xor(q, o);
  if (lane == 0) sA[wv] = q;

  if (tid < A_DIM) {
    float s = 0.f;
    for (int d = 0; d < D_DIM; ++d) { const float w = Wt[d*A_DIM + tid]; s += w*w; }
    cninv[tid] = 1.0f / fmaxf(sqrtf(s), EPS_);
  }
  __syncthreads();
  if (wv == 0) {
    float s = (lane < 16) ? sA[lane] : 0.f;
    #pragma unroll
    for (int o = 32; o > 0; o >>= 1) s += __shfl_xor(s, o);
    if (lane == 0) quad_s = s;
  }
  __syncthreads();

  const float p = 0.5f*quad_s + linb[tid] + fcb[0]
                + busers[user[tid]] + bitems[item[tid]];
  pred[tid] = p;
  const float dd = p - label[tid];
  const float myrl = dd*dd;
  rl[tid] = myrl;

  float u = 0.f;
  if (tid < 400) {
    const int a = tid / 20, c = tid % 20;
    float dot = 0.f;
    for (int d = 0; d < D_DIM; ++d) dot += Wt[d*A_DIM + a]*Wt[d*A_DIM + c];
    const float g = dot*cninv[a]*cninv[c] - (a==c ? 1.0f : 0.0f);
    u = g*g;
  }
  float js = 0.f;
  #pragma unroll
  for (int j = 0; j < 8; ++j) js += abae[tid + 1024*j];
  float ms = myrl;

  #pragma unroll
  for (int o = 32; o > 0; o >>= 1) {
    u += __shfl_xor(u,o); js += __shfl_xor(js,o); ms += __shfl_xor(ms,o);
  }
  if (lane == 0) { sA[wv] = u; sB[wv] = js; sC[wv] = ms; }
  __syncthreads();
  if (tid == 0) {
    float U = 0.f, J = 0.f, Ms = 0.f;
    for (int i = 0; i < 16; ++i) { U += sA[i]; J += sB[i]; Ms += sC[i]; }
    obj[0] = Ms/1024.0f + 0.01f*(J/8192.0f) + 0.01f*(U/400.0f);
  }
}

extern "C" void kernel_launch(void* const* d_in, const int* in_sizes, int n_in,
                              void* d_out, int out_size, void* d_ws, size_t ws_size,
                              hipStream_t stream) {
  const int*   hist   = (const int*)  d_in[0];
  const int*   neg    = (const int*)  d_in[1];
  const int*   user   = (const int*)  d_in[2];
  const int*   item   = (const int*)  d_in[3];
  const float* label  = (const float*)d_in[4];
  const int*   uidx   = (const int*)  d_in[5];
  const float* uval   = (const float*)d_in[6];
  const int*   iidx   = (const int*)  d_in[7];
  const float* ival   = (const float*)d_in[8];
  const float* emb    = (const float*)d_in[9];
  const float* Wm     = (const float*)d_in[10];
  const float* Ww     = (const float*)d_in[11];
  const float* bw     = (const float*)d_in[12];
  const float* Wt     = (const float*)d_in[13];
  const float* fcw    = (const float*)d_in[14];
  const float* fcb    = (const float*)d_in[15];
  const float* V      = (const float*)d_in[16];
  const float* busers = (const float*)d_in[17];
  const float* bitems = (const float*)d_in[18];

  float* out  = (float*)d_out;
  float* obj  = out;                       // 1
  float* rl   = out + 1;                   // 1024
  float* abae = out + 1 + B_SZ;            // 8192
  float* pred = out + 1 + B_SZ + RN_TOT;   // 1024
  float* uae  = pred + B_SZ;               // 204800
  float* iae  = uae + (size_t)B_SZ*D_DIM;  // 204800

  float* ws     = (float*)d_ws;
  float* rs     = ws;                              // R*D
  float* ys_all = rs + (size_t)R_TOT*D_DIM;        // R*D
  float* zn_all = ys_all + (size_t)R_TOT*D_DIM;    // RN*D
  float* vv_all = zn_all + (size_t)RN_TOT*D_DIM;   // R*D
  float* linb   = vv_all + (size_t)R_TOT*D_DIM;    // B
  float* quadb  = linb + B_SZ;                     // B
  float* sval   = quadb + B_SZ;                    // 2*B*SLOT_CAP floats
  int*   scol   = (int*)(sval + (size_t)2*B_SZ*SLOT_CAP);   // 2*B*SLOT_CAP ints
  int*   cnt    = scol + (size_t)2*B_SZ*SLOT_CAP;           // 2*B ints
  ushort* emb_h = (ushort*)(cnt + 2*B_SZ);                  // VOCAB*D halves

  const int cast_blocks = (VOCAB_C*D_DIM/4 + 255)/256;      // 6250

  k_cast  <<<cast_blocks, 256, 0, stream>>>(emb, emb_h, cnt);
  k_means2<<<S_TOT + NBUCK_BLK, 256, 0, stream>>>(hist, neg, emb_h,
                                                  ys_all, zn_all,
                                                  uidx, uval, iidx, ival,
                                                  cnt, scol, sval);
  k_matvec<<<R_TOT/KB_RT, 256, 0, stream>>>(ys_all, Wm, vv_all);
  k_attn  <<<R_TOT, 512, 0, stream>>>(hist, emb_h, vv_all, Ww, bw, Wt,
                                      zn_all, rs, abae);
  k_aggfm <<<B_SZ, 512, 0, stream>>>(cnt, scol, sval, rs, fcw, V,
                                     uae, iae, linb, quadb);
  k_final2<<<1, 1024, 0, stream>>>(quadb, linb, fcb, user, item, busers, bitems,
                                   label, Wt, abae, pred, rl, obj);
}